// Round 13
// baseline (151.275 us; speedup 1.0000x reference)
//
#include <hip/hip_runtime.h>
#include <hip/hip_bf16.h>

#define D_MSA 384
#define NHEAD 12
#define DHID  32
#define BB    2
#define NN    256
#define LL    384
#define NBL   (BB * LL)          // 768 (b,l) pairs
#define WFROW (NHEAD * D_MSA)    // 4608

// ---- workspace layout (in floats) ----
#define WF_OFF 0
#define WF_SZ  ((size_t)NBL * WFROW)       // 3,538,944
#define Q_OFF  (WF_OFF + WF_SZ)
#define Q_SZ   ((size_t)NBL * D_MSA)       // 294,912
#define CB_OFF (Q_OFF + Q_SZ)
#define CB_SZ  ((size_t)NBL * NHEAD)       // 9,216
#define LOG_OFF (CB_OFF + CB_SZ)
#define LOG_SZ ((size_t)NBL * NHEAD * NN)  // 2,359,296
#define WS_FLOATS (LOG_OFF + LOG_SZ)
#define WS_BYTES  (WS_FLOATS * 4)

// =====================================================================
// A1: q[bl][c] = scale*(tar[bl] . Wq[c,:] + bq[c]); cb[bl][h] = q_h . bk_h
// 256 blocks x 3 bl-rows, 256 thr (round-9 proven, unchanged).
// =====================================================================
__global__ __launch_bounds__(256)
void seqw_a1(const float* __restrict__ msa, const float* __restrict__ Wq,
             const float* __restrict__ bq, const float* __restrict__ bk,
             float* __restrict__ q_ws, float* __restrict__ cb_ws)
{
  __shared__ float tar[3][D_MSA];
  __shared__ float qs[3][D_MSA];
  const int t    = threadIdx.x;
  const int lane = t & 63;
  const int wv   = t >> 6;        // 0..3
  const int rowi = lane >> 4;     // 0..3
  const int seg  = lane & 15;     // 0..15
  const int bl0  = blockIdx.x * 3;
  const int b    = bl0 / LL, l0 = bl0 % LL;  // 3 | 384, never straddles b
  const float scale = 0.17677669529663687f;  // 1/sqrt(32)

  const float* base = msa + ((size_t)b * NN * LL + l0) * D_MSA;
  for (int i = t; i < 3 * D_MSA / 4; i += 256)
    ((float4*)tar)[i] = ((const float4*)base)[i];
  __syncthreads();

#pragma unroll 1
  for (int cc = 0; cc < 24; ++cc) {
    const int c = wv * 96 + cc * 4 + rowi;
    const float* wr = Wq + (size_t)c * D_MSA + seg * 4;
    float a0 = 0.f, a1 = 0.f, a2 = 0.f;
#pragma unroll
    for (int j = 0; j < 6; ++j) {
      float4 w4 = *(const float4*)(wr + 64 * j);
      float4 t0 = *(const float4*)&tar[0][64 * j + seg * 4];
      float4 t1 = *(const float4*)&tar[1][64 * j + seg * 4];
      float4 t2 = *(const float4*)&tar[2][64 * j + seg * 4];
      a0 = fmaf(w4.x, t0.x, a0); a0 = fmaf(w4.y, t0.y, a0);
      a0 = fmaf(w4.z, t0.z, a0); a0 = fmaf(w4.w, t0.w, a0);
      a1 = fmaf(w4.x, t1.x, a1); a1 = fmaf(w4.y, t1.y, a1);
      a1 = fmaf(w4.z, t1.z, a1); a1 = fmaf(w4.w, t1.w, a1);
      a2 = fmaf(w4.x, t2.x, a2); a2 = fmaf(w4.y, t2.y, a2);
      a2 = fmaf(w4.z, t2.z, a2); a2 = fmaf(w4.w, t2.w, a2);
    }
#pragma unroll
    for (int m = 8; m; m >>= 1) {
      a0 += __shfl_xor(a0, m);
      a1 += __shfl_xor(a1, m);
      a2 += __shfl_xor(a2, m);
    }
    if (seg == 0) {
      const float bqc = bq[c];
      const float q0 = scale * (a0 + bqc);
      const float q1 = scale * (a1 + bqc);
      const float q2 = scale * (a2 + bqc);
      qs[0][c] = q0; q_ws[(size_t)(bl0 + 0) * D_MSA + c] = q0;
      qs[1][c] = q1; q_ws[(size_t)(bl0 + 1) * D_MSA + c] = q1;
      qs[2][c] = q2; q_ws[(size_t)(bl0 + 2) * D_MSA + c] = q2;
    }
  }
  __syncthreads();

  if (t < 3 * NHEAD) {
    const int r = t / NHEAD, h = t % NHEAD;
    float s = 0.f;
#pragma unroll
    for (int d = 0; d < DHID; ++d)
      s = fmaf(qs[r][h * DHID + d], bk[h * DHID + d], s);
    cb_ws[(size_t)(bl0 + r) * NHEAD + h] = s;
  }
}

// =====================================================================
// A2: wf[bl][h][c] = sum_d q[bl][h*32+d] * Wk[h*32+d][c]
// grid 12h x 48 tiles of 16 bl-rows, 256 threads (round-9 proven).
// =====================================================================
__global__ __launch_bounds__(256)
void seqw_a2(const float* __restrict__ Wk, const float* __restrict__ q_ws,
             float* __restrict__ wf_ws)
{
  __shared__ float qt[16][DHID];
  const int t   = threadIdx.x;
  const int h   = blockIdx.x % NHEAD;
  const int bl0 = (blockIdx.x / NHEAD) * 16;

  if (t < 128) {
    const int r = t >> 3, j = (t & 7) * 4;
    *(float4*)&qt[r][j] =
        *(const float4*)(q_ws + (size_t)(bl0 + r) * D_MSA + h * DHID + j);
  }
  __syncthreads();

#pragma unroll 1
  for (int pass = 0; pass < 2; ++pass) {
    const int c = pass * 256 + t;
    if (c < D_MSA) {
      float acc[16];
#pragma unroll
      for (int r = 0; r < 16; ++r) acc[r] = 0.f;
      const float* wkb = Wk + (size_t)(h * DHID) * D_MSA + c;
#pragma unroll 2
      for (int d = 0; d < DHID; d += 4) {
        const float w0 = wkb[(size_t)(d + 0) * D_MSA];
        const float w1 = wkb[(size_t)(d + 1) * D_MSA];
        const float w2 = wkb[(size_t)(d + 2) * D_MSA];
        const float w3 = wkb[(size_t)(d + 3) * D_MSA];
#pragma unroll
        for (int r = 0; r < 16; ++r) {
          float4 q4 = *(const float4*)&qt[r][d];
          acc[r] = fmaf(q4.x, w0, acc[r]);
          acc[r] = fmaf(q4.y, w1, acc[r]);
          acc[r] = fmaf(q4.z, w2, acc[r]);
          acc[r] = fmaf(q4.w, w3, acc[r]);
        }
      }
#pragma unroll
      for (int r = 0; r < 16; ++r)
        wf_ws[(size_t)(bl0 + r) * WFROW + h * D_MSA + c] = acc[r];
    }
  }
}

// =====================================================================
// B: logits only. Grid 3072 = (bl, n-quarter); 256 thr = 4 waves.
// ROUND-13 CHANGE: no LDS staging of wf — CPB reads wf directly from
// global. Per (h,j) the 64 lanes touch one contiguous 128B line (8-way
// broadcast within seg groups) -> L1-served after first touch; block's
// 18KB slice is L1/L2-resident. No pre-loop barrier; LDS drops to 3KB
// (attn_s only) -> more resident blocks for latency hiding.
// Wave wv: head-group hg = wv&1 (6 heads), row-half rq = wv>>1 (32 of
// 64 rows). Lanes = 8 rowi x 8 seg; 128B/row coalesced loads; G=4 rows
// per wf read. acc[4][6]=24 regs. 3-stage shfl reduce.
// NO min-occupancy launch_bounds (spill trap, r2/5/6).
// =====================================================================
__global__ __launch_bounds__(256)
void seqw_b(const float* __restrict__ msa, const float* __restrict__ wf_ws,
            const float* __restrict__ cb_ws, float* __restrict__ log_ws)
{
  __shared__ float attn_s[NHEAD][64];    // 3 KB
  const int t    = threadIdx.x;
  const int lane = t & 63;
  const int wv   = t >> 6;        // 0..3
  const int hg   = wv & 1;        // head group: h0 = 6*hg
  const int rq   = wv >> 1;       // row half: rows [rq*32, rq*32+32)
  const int h0   = 6 * hg;
  const int rowi = lane >> 3;     // 0..7
  const int seg  = lane & 7;      // 0..7 : 8 lanes cover 32 c per j-step
  const int bid  = blockIdx.x;
  const int bl   = bid >> 2;
  const int nq   = bid & 3;       // which 64-row quarter
  const int b    = bl / LL;
  const int l    = bl - b * LL;

  const float* wfb = wf_ws + (size_t)bl * WFROW + (size_t)h0 * D_MSA + 4 * seg;

  const size_t rstride = (size_t)LL * D_MSA;
  const float* lanebase =
      msa + ((size_t)(b * NN + nq * 64 + rq * 32 + rowi) * LL + l) * D_MSA + seg * 4;

  // LDB: 4 row-groups; 8-lane seg group reads 128B contiguous per row
#define LDB(buf, j)                                                             \
  {                                                                             \
    _Pragma("unroll")                                                           \
    for (int g = 0; g < 4; ++g)                                                 \
      buf[g] = *(const float4*)(lanebase + (size_t)(g * 8) * rstride + 32 * (j)); \
  }
  // CPB: 6 global wf reads (128B broadcast lines, L1) serve 4 rows x 6 heads
#define CPB(buf, j)                                                             \
  {                                                                             \
    _Pragma("unroll")                                                           \
    for (int hh = 0; hh < 6; ++hh) {                                            \
      float4 w4 = *(const float4*)(wfb + (size_t)hh * D_MSA + 32 * (j));        \
      _Pragma("unroll")                                                         \
      for (int g = 0; g < 4; ++g) {                                             \
        acc[g][hh] = fmaf(buf[g].x, w4.x, acc[g][hh]);                          \
        acc[g][hh] = fmaf(buf[g].y, w4.y, acc[g][hh]);                          \
        acc[g][hh] = fmaf(buf[g].z, w4.z, acc[g][hh]);                          \
        acc[g][hh] = fmaf(buf[g].w, w4.w, acc[g][hh]);                          \
      }                                                                         \
    }                                                                           \
  }

  float acc[4][6];
#pragma unroll
  for (int g = 0; g < 4; ++g)
#pragma unroll
    for (int hh = 0; hh < 6; ++hh) acc[g][hh] = 0.f;

  float4 bufA[4], bufB[4];
  LDB(bufA, 0)
#pragma unroll 1
  for (int jj = 0; jj < 6; ++jj) {
    const int j0 = 2 * jj, j1 = 2 * jj + 1;
    LDB(bufB, j1)
    CPB(bufA, j0)
    if (jj < 5) LDB(bufA, j0 + 2)
    CPB(bufB, j1)
  }

  // reduce over the 8-seg group (3 stages), add cb, write logits to LDS
  const float* cbb = cb_ws + (size_t)bl * NHEAD + h0;
#pragma unroll
  for (int g = 0; g < 4; ++g) {
#pragma unroll
    for (int hh = 0; hh < 6; ++hh) {
      float s = acc[g][hh];
      s += __shfl_xor(s, 4);
      s += __shfl_xor(s, 2);
      s += __shfl_xor(s, 1);
      if (seg == 0)
        attn_s[h0 + hh][rq * 32 + g * 8 + rowi] = s + cbb[hh];
    }
  }
  __syncthreads();

  // coalesced store: log_ws[bl][h][nq*64 .. +64), per-bl stride 768 f4
  for (int i = t; i < NHEAD * 64 / 4; i += 256) {
    const int h = i >> 4, r4 = i & 15;
    ((float4*)log_ws)[(size_t)bl * (NHEAD * NN / 4) + h * (NN / 4) + nq * 16 + r4] =
        ((const float4*)attn_s)[i];
  }
}

// =====================================================================
// C: softmax over n per (bl, h) + write out[b][n][l][h]. 768 blocks
// (round-9 proven, unchanged).
// =====================================================================
__global__ __launch_bounds__(256)
void seqw_c(const float* __restrict__ log_ws, float* __restrict__ out)
{
  __shared__ float at[NHEAD][NN];
  __shared__ float smax[NHEAD], sinv[NHEAD];
  const int t    = threadIdx.x;
  const int lane = t & 63;
  const int wv   = t >> 6;
  const int bl   = blockIdx.x;
  const int b    = bl / LL;
  const int l    = bl - b * LL;

  for (int i = t; i < NHEAD * NN / 4; i += 256)
    ((float4*)at)[i] = ((const float4*)log_ws)[(size_t)bl * (NHEAD * NN / 4) + i];
  __syncthreads();

#pragma unroll
  for (int jh = 0; jh < 3; ++jh) {
    const int h = wv * 3 + jh;
    float v0 = at[h][lane];
    float v1 = at[h][lane + 64];
    float v2 = at[h][lane + 128];
    float v3 = at[h][lane + 192];
    float mx = fmaxf(fmaxf(v0, v1), fmaxf(v2, v3));
#pragma unroll
    for (int m = 32; m; m >>= 1) mx = fmaxf(mx, __shfl_xor(mx, m));
    float s = __expf(v0 - mx) + __expf(v1 - mx) + __expf(v2 - mx) + __expf(v3 - mx);
#pragma unroll
    for (int m = 32; m; m >>= 1) s += __shfl_xor(s, m);
    if (lane == 0) { smax[h] = mx; sinv[h] = 1.0f / s; }
  }
  __syncthreads();

  {
    float o[NHEAD];
#pragma unroll
    for (int h = 0; h < NHEAD; ++h)
      o[h] = __expf(at[h][t] - smax[h]) * sinv[h];
    float* ob = out + ((size_t)(b * NN + t) * LL + l) * NHEAD;
    ((float4*)ob)[0] = make_float4(o[0], o[1], o[2],  o[3]);
    ((float4*)ob)[1] = make_float4(o[4], o[5], o[6],  o[7]);
    ((float4*)ob)[2] = make_float4(o[8], o[9], o[10], o[11]);
  }
}

// =====================================================================
// Fallback: fused single kernel (only if ws too small) — round-3 proven.
// =====================================================================
struct SmemF {
  float tar[D_MSA];
  float q[D_MSA];
  float wf[NHEAD][D_MSA];
  float cb[NHEAD];
  float smax[NHEAD];
  float sinv[NHEAD];
  float attn[NHEAD][NN];
};

__global__ __launch_bounds__(512, 2)
void seqw_fused_fb(const float* __restrict__ msa, const float* __restrict__ Wq,
                   const float* __restrict__ bq, const float* __restrict__ Wk,
                   const float* __restrict__ bk, float* __restrict__ out)
{
  __shared__ SmemF sm;
  const int t    = threadIdx.x;
  const int lane = t & 63;
  const int wv   = t >> 6;
  const int rowi = lane >> 4;
  const int seg  = lane & 15;
  const int bl   = blockIdx.x;
  const int b    = bl / LL;
  const int l    = bl - b * LL;
  const float scale = 0.17677669529663687f;

  const float* targ = msa + ((size_t)(b * NN) * LL + l) * D_MSA;
  if (t < 96) ((float4*)sm.tar)[t] = ((const float4*)targ)[t];
  __syncthreads();

  {
    float2 t2[3];
#pragma unroll
    for (int p = 0; p < 3; ++p) t2[p] = *(const float2*)&sm.tar[2 * lane + 128 * p];
#pragma unroll 1
    for (int j = 0; j < 48; ++j) {
      const int r = wv * 48 + j;
      const float* wr = Wq + (size_t)r * D_MSA;
      float s = 0.f;
#pragma unroll
      for (int p = 0; p < 3; ++p) {
        float2 w2 = *(const float2*)&wr[2 * lane + 128 * p];
        s = fmaf(t2[p].x, w2.x, s);
        s = fmaf(t2[p].y, w2.y, s);
      }
#pragma unroll
      for (int m = 32; m; m >>= 1) s += __shfl_xor(s, m);
      if (lane == 0) sm.q[r] = scale * (s + bq[r]);
    }
  }
  __syncthreads();

  if (t < D_MSA) {
    const int c = t;
    float a[NHEAD];
#pragma unroll
    for (int h = 0; h < NHEAD; ++h) a[h] = 0.f;
#pragma unroll 1
    for (int d = 0; d < DHID; ++d) {
#pragma unroll
      for (int h = 0; h < NHEAD; ++h)
        a[h] = fmaf(sm.q[h * DHID + d], Wk[(size_t)(h * DHID + d) * D_MSA + c], a[h]);
    }
#pragma unroll
    for (int h = 0; h < NHEAD; ++h) sm.wf[h][c] = a[h];
  }
  if (t < NHEAD) {
    float s = 0.f;
#pragma unroll
    for (int d = 0; d < DHID; ++d) s = fmaf(sm.q[t * DHID + d], bk[t * DHID + d], s);
    sm.cb[t] = s;
  }
  __syncthreads();

  const size_t rstride = (size_t)LL * D_MSA;
  const float* lanebase =
      msa + ((size_t)(b * NN + wv * 32 + rowi) * LL + l) * D_MSA + seg * 4;

#define LDF(buf, base, j)                                                       \
  {                                                                             \
    buf[0] = *(const float4*)((base) + 64 * (j));                               \
    buf[1] = *(const float4*)((base) + 4 * rstride + 64 * (j));                 \
  }
#define CPF(buf, j)                                                             \
  {                                                                             \
    _Pragma("unroll")                                                           \
    for (int h = 0; h < NHEAD; ++h) {                                           \
      float4 w4 = *(const float4*)&sm.wf[h][64 * (j) + 4 * seg];                \
      acc[0][h] = fmaf(buf[0].x, w4.x, acc[0][h]);                              \
      acc[0][h] = fmaf(buf[0].y, w4.y, acc[0][h]);                              \
      acc[0][h] = fmaf(buf[0].z, w4.z, acc[0][h]);                              \
      acc[0][h] = fmaf(buf[0].w, w4.w, acc[0][h]);                              \
      acc[1][h] = fmaf(buf[1].x, w4.x, acc[1][h]);                              \
      acc[1][h] = fmaf(buf[1].y, w4.y, acc[1][h]);                              \
      acc[1][h] = fmaf(buf[1].z, w4.z, acc[1][h]);                              \
      acc[1][h] = fmaf(buf[1].w, w4.w, acc[1][h]);                              \
    }                                                                           \
  }

  const float* pcur = lanebase;
  float4 bufA[2], bufB[2];
  LDF(bufA, pcur, 0)
#pragma unroll 1
  for (int ch = 0; ch < 4; ++ch) {
    float acc[2][NHEAD];
#pragma unroll
    for (int g = 0; g < 2; ++g)
#pragma unroll
      for (int h = 0; h < NHEAD; ++h) acc[g][h] = 0.f;
    const float* pnext = pcur + 8 * rstride;
    LDF(bufB, pcur, 1)  CPF(bufA, 0)
    LDF(bufA, pcur, 2)  CPF(bufB, 1)
    LDF(bufB, pcur, 3)  CPF(bufA, 2)
    LDF(bufA, pcur, 4)  CPF(bufB, 3)
    LDF(bufB, pcur, 5)  CPF(bufA, 4)
    if (ch < 3) LDF(bufA, pnext, 0)
    CPF(bufB, 5)
#pragma unroll
    for (int g = 0; g < 2; ++g) {
      const int n = wv * 32 + ch * 8 + g * 4 + rowi;
#pragma unroll
      for (int h = 0; h < NHEAD; ++h) {
        float s = acc[g][h];
        s += __shfl_xor(s, 8);
        s += __shfl_xor(s, 4);
        s += __shfl_xor(s, 2);
        s += __shfl_xor(s, 1);
        if (seg == 0) sm.attn[h][n] = s + sm.cb[h];
      }
    }
    pcur = pnext;
  }
  __syncthreads();

  if (wv < 6) {
#pragma unroll
    for (int jh = 0; jh < 2; ++jh) {
      const int h = wv * 2 + jh;
      float v0 = sm.attn[h][lane];
      float v1 = sm.attn[h][lane + 64];
      float v2 = sm.attn[h][lane + 128];
      float v3 = sm.attn[h][lane + 192];
      float mx = fmaxf(fmaxf(v0, v1), fmaxf(v2, v3));
#pragma unroll
      for (int m = 32; m; m >>= 1) mx = fmaxf(mx, __shfl_xor(mx, m));
      float s = __expf(v0 - mx) + __expf(v1 - mx) + __expf(v2 - mx) + __expf(v3 - mx);
#pragma unroll
      for (int m = 32; m; m >>= 1) s += __shfl_xor(s, m);
      if (lane == 0) { sm.smax[h] = mx; sm.sinv[h] = 1.0f / s; }
    }
  }
  __syncthreads();

  if (t < NN) {
    float o[NHEAD];
#pragma unroll
    for (int h = 0; h < NHEAD; ++h)
      o[h] = __expf(sm.attn[h][t] - sm.smax[h]) * sm.sinv[h];
    float* ob = out + ((size_t)(b * NN + t) * LL + l) * NHEAD;
    ((float4*)ob)[0] = make_float4(o[0], o[1], o[2],  o[3]);
    ((float4*)ob)[1] = make_float4(o[4], o[5], o[6],  o[7]);
    ((float4*)ob)[2] = make_float4(o[8], o[9], o[10], o[11]);
  }
}

extern "C" void kernel_launch(void* const* d_in, const int* in_sizes, int n_in,
                              void* d_out, int out_size, void* d_ws, size_t ws_size,
                              hipStream_t stream) {
  const float* msa = (const float*)d_in[0];
  const float* Wq  = (const float*)d_in[1];
  const float* bq  = (const float*)d_in[2];
  const float* Wk  = (const float*)d_in[3];
  const float* bk  = (const float*)d_in[4];
  float* out = (float*)d_out;

  if (ws_size >= WS_BYTES) {
    float* ws     = (float*)d_ws;
    float* wf_ws  = ws + WF_OFF;
    float* q_ws   = ws + Q_OFF;
    float* cb_ws  = ws + CB_OFF;
    float* log_ws = ws + LOG_OFF;
    seqw_a1<<<dim3(NBL / 3), dim3(256), 0, stream>>>(msa, Wq, bq, bk, q_ws, cb_ws);
    seqw_a2<<<dim3(NHEAD * (NBL / 16)), dim3(256), 0, stream>>>(Wk, q_ws, wf_ws);
    seqw_b<<<dim3(NBL * 4), dim3(256), 0, stream>>>(msa, wf_ws, cb_ws, log_ws);
    seqw_c<<<dim3(NBL), dim3(256), 0, stream>>>(log_ws, out);
  } else {
    seqw_fused_fb<<<dim3(NBL), dim3(512), 0, stream>>>(msa, Wq, bq, Wk, bk, out);
  }
}

// Round 14
// 130.542 us; speedup vs baseline: 1.1588x; 1.1588x over previous
//
#include <hip/hip_runtime.h>
#include <hip/hip_bf16.h>

#define D_MSA 384
#define NHEAD 12
#define DHID  32
#define BB    2
#define NN    256
#define LL    384
#define NBL   (BB * LL)          // 768 (b,l) pairs
#define WFROW (NHEAD * D_MSA)    // 4608

// ---- workspace layout (in floats) ----
#define WF_OFF 0
#define WF_SZ  ((size_t)NBL * WFROW)       // 3,538,944
#define Q_OFF  (WF_OFF + WF_SZ)
#define Q_SZ   ((size_t)NBL * D_MSA)       // 294,912
#define CB_OFF (Q_OFF + Q_SZ)
#define CB_SZ  ((size_t)NBL * NHEAD)       // 9,216
#define LOG_OFF (CB_OFF + CB_SZ)
#define LOG_SZ ((size_t)NBL * NHEAD * NN)  // 2,359,296
#define WS_FLOATS (LOG_OFF + LOG_SZ)
#define WS_BYTES  (WS_FLOATS * 4)

// =====================================================================
// A1: q[bl][c] = scale*(tar[bl] . Wq[c,:] + bq[c]); cb[bl][h] = q_h . bk_h
// 256 blocks x 3 bl-rows, 256 thr (round-9 proven, unchanged).
// =====================================================================
__global__ __launch_bounds__(256)
void seqw_a1(const float* __restrict__ msa, const float* __restrict__ Wq,
             const float* __restrict__ bq, const float* __restrict__ bk,
             float* __restrict__ q_ws, float* __restrict__ cb_ws)
{
  __shared__ float tar[3][D_MSA];
  __shared__ float qs[3][D_MSA];
  const int t    = threadIdx.x;
  const int lane = t & 63;
  const int wv   = t >> 6;        // 0..3
  const int rowi = lane >> 4;     // 0..3
  const int seg  = lane & 15;     // 0..15
  const int bl0  = blockIdx.x * 3;
  const int b    = bl0 / LL, l0 = bl0 % LL;  // 3 | 384, never straddles b
  const float scale = 0.17677669529663687f;  // 1/sqrt(32)

  const float* base = msa + ((size_t)b * NN * LL + l0) * D_MSA;
  for (int i = t; i < 3 * D_MSA / 4; i += 256)
    ((float4*)tar)[i] = ((const float4*)base)[i];
  __syncthreads();

#pragma unroll 1
  for (int cc = 0; cc < 24; ++cc) {
    const int c = wv * 96 + cc * 4 + rowi;
    const float* wr = Wq + (size_t)c * D_MSA + seg * 4;
    float a0 = 0.f, a1 = 0.f, a2 = 0.f;
#pragma unroll
    for (int j = 0; j < 6; ++j) {
      float4 w4 = *(const float4*)(wr + 64 * j);
      float4 t0 = *(const float4*)&tar[0][64 * j + seg * 4];
      float4 t1 = *(const float4*)&tar[1][64 * j + seg * 4];
      float4 t2 = *(const float4*)&tar[2][64 * j + seg * 4];
      a0 = fmaf(w4.x, t0.x, a0); a0 = fmaf(w4.y, t0.y, a0);
      a0 = fmaf(w4.z, t0.z, a0); a0 = fmaf(w4.w, t0.w, a0);
      a1 = fmaf(w4.x, t1.x, a1); a1 = fmaf(w4.y, t1.y, a1);
      a1 = fmaf(w4.z, t1.z, a1); a1 = fmaf(w4.w, t1.w, a1);
      a2 = fmaf(w4.x, t2.x, a2); a2 = fmaf(w4.y, t2.y, a2);
      a2 = fmaf(w4.z, t2.z, a2); a2 = fmaf(w4.w, t2.w, a2);
    }
#pragma unroll
    for (int m = 8; m; m >>= 1) {
      a0 += __shfl_xor(a0, m);
      a1 += __shfl_xor(a1, m);
      a2 += __shfl_xor(a2, m);
    }
    if (seg == 0) {
      const float bqc = bq[c];
      const float q0 = scale * (a0 + bqc);
      const float q1 = scale * (a1 + bqc);
      const float q2 = scale * (a2 + bqc);
      qs[0][c] = q0; q_ws[(size_t)(bl0 + 0) * D_MSA + c] = q0;
      qs[1][c] = q1; q_ws[(size_t)(bl0 + 1) * D_MSA + c] = q1;
      qs[2][c] = q2; q_ws[(size_t)(bl0 + 2) * D_MSA + c] = q2;
    }
  }
  __syncthreads();

  if (t < 3 * NHEAD) {
    const int r = t / NHEAD, h = t % NHEAD;
    float s = 0.f;
#pragma unroll
    for (int d = 0; d < DHID; ++d)
      s = fmaf(qs[r][h * DHID + d], bk[h * DHID + d], s);
    cb_ws[(size_t)(bl0 + r) * NHEAD + h] = s;
  }
}

// =====================================================================
// A2: wf[bl][h][c] = sum_d q[bl][h*32+d] * Wk[h*32+d][c]
// grid 12h x 48 tiles of 16 bl-rows, 256 threads (round-9 proven).
// =====================================================================
__global__ __launch_bounds__(256)
void seqw_a2(const float* __restrict__ Wk, const float* __restrict__ q_ws,
             float* __restrict__ wf_ws)
{
  __shared__ float qt[16][DHID];
  const int t   = threadIdx.x;
  const int h   = blockIdx.x % NHEAD;
  const int bl0 = (blockIdx.x / NHEAD) * 16;

  if (t < 128) {
    const int r = t >> 3, j = (t & 7) * 4;
    *(float4*)&qt[r][j] =
        *(const float4*)(q_ws + (size_t)(bl0 + r) * D_MSA + h * DHID + j);
  }
  __syncthreads();

#pragma unroll 1
  for (int pass = 0; pass < 2; ++pass) {
    const int c = pass * 256 + t;
    if (c < D_MSA) {
      float acc[16];
#pragma unroll
      for (int r = 0; r < 16; ++r) acc[r] = 0.f;
      const float* wkb = Wk + (size_t)(h * DHID) * D_MSA + c;
#pragma unroll 2
      for (int d = 0; d < DHID; d += 4) {
        const float w0 = wkb[(size_t)(d + 0) * D_MSA];
        const float w1 = wkb[(size_t)(d + 1) * D_MSA];
        const float w2 = wkb[(size_t)(d + 2) * D_MSA];
        const float w3 = wkb[(size_t)(d + 3) * D_MSA];
#pragma unroll
        for (int r = 0; r < 16; ++r) {
          float4 q4 = *(const float4*)&qt[r][d];
          acc[r] = fmaf(q4.x, w0, acc[r]);
          acc[r] = fmaf(q4.y, w1, acc[r]);
          acc[r] = fmaf(q4.z, w2, acc[r]);
          acc[r] = fmaf(q4.w, w3, acc[r]);
        }
      }
#pragma unroll
      for (int r = 0; r < 16; ++r)
        wf_ws[(size_t)(bl0 + r) * WFROW + h * D_MSA + c] = acc[r];
    }
  }
}

// =====================================================================
// B: logits only. Grid 3072 = (bl, n-quarter); 256 thr = 4 waves.
// ROUND-14 CHANGE (only change vs round 12): chunked XCD swizzle.
// Dispatch i runs on XCD i%8; remap so XCD k owns contiguous bids
// [k*384,(k+1)*384) = bl range [k*96,(k+1)*96): per-XCD L2 sees
// contiguous 147KB msa spans per (b,n) row instead of 128B/1536B
// stride, and all 4 quarters of a bl (sharing the wf slice) colocate.
// Wave wv: head-group hg = wv&1 (6 heads), row-half rq = wv>>1.
// Lanes = 8 rowi x 8 seg; 128B/row coalesced loads; wf staged in LDS
// (round-13 showed global-direct wf costs +21us). acc[4][6]=24 regs.
// NO min-occupancy launch_bounds (spill trap, r2/5/6).
// =====================================================================
__global__ __launch_bounds__(256)
void seqw_b(const float* __restrict__ msa, const float* __restrict__ wf_ws,
            const float* __restrict__ cb_ws, float* __restrict__ log_ws)
{
  __shared__ float wf_s[NHEAD][D_MSA];   // 18 KB
  __shared__ float cb_s[NHEAD];
  __shared__ float attn_s[NHEAD][64];    // 3 KB
  const int t    = threadIdx.x;
  const int lane = t & 63;
  const int wv   = t >> 6;        // 0..3
  const int hg   = wv & 1;        // head group: h0 = 6*hg
  const int rq   = wv >> 1;       // row half: rows [rq*32, rq*32+32)
  const int h0   = 6 * hg;
  const int rowi = lane >> 3;     // 0..7
  const int seg  = lane & 7;      // 0..7 : 8 lanes cover 32 c per j-step
  // chunked XCD swizzle (bijective: 3072 % 8 == 0)
  const int i0   = blockIdx.x;
  const int bid  = (i0 & 7) * (NBL * 4 / 8) + (i0 >> 3);
  const int bl   = bid >> 2;
  const int nq   = bid & 3;       // which 64-row quarter
  const int b    = bl / LL;
  const int l    = bl - b * LL;

  // stage wf slice (1152 float4, coalesced; 4 quarters share via L2) + cb
  {
    const float4* src = (const float4*)(wf_ws + (size_t)bl * WFROW);
    for (int i = t; i < WFROW / 4; i += 256) ((float4*)wf_s)[i] = src[i];
    if (t < NHEAD) cb_s[t] = cb_ws[(size_t)bl * NHEAD + t];
  }
  __syncthreads();

  const size_t rstride = (size_t)LL * D_MSA;
  const float* lanebase =
      msa + ((size_t)(b * NN + nq * 64 + rq * 32 + rowi) * LL + l) * D_MSA + seg * 4;

  // LDB: 4 row-groups; 8-lane seg group reads 128B contiguous per row
#define LDB(buf, j)                                                             \
  {                                                                             \
    _Pragma("unroll")                                                           \
    for (int g = 0; g < 4; ++g)                                                 \
      buf[g] = *(const float4*)(lanebase + (size_t)(g * 8) * rstride + 32 * (j)); \
  }
  // CPB: 6 w4 reads serve 4 rows x 6 heads
#define CPB(buf, j)                                                             \
  {                                                                             \
    _Pragma("unroll")                                                           \
    for (int hh = 0; hh < 6; ++hh) {                                            \
      float4 w4 = *(const float4*)&wf_s[h0 + hh][32 * (j) + 4 * seg];           \
      _Pragma("unroll")                                                         \
      for (int g = 0; g < 4; ++g) {                                             \
        acc[g][hh] = fmaf(buf[g].x, w4.x, acc[g][hh]);                          \
        acc[g][hh] = fmaf(buf[g].y, w4.y, acc[g][hh]);                          \
        acc[g][hh] = fmaf(buf[g].z, w4.z, acc[g][hh]);                          \
        acc[g][hh] = fmaf(buf[g].w, w4.w, acc[g][hh]);                          \
      }                                                                         \
    }                                                                           \
  }

  float acc[4][6];
#pragma unroll
  for (int g = 0; g < 4; ++g)
#pragma unroll
    for (int hh = 0; hh < 6; ++hh) acc[g][hh] = 0.f;

  float4 bufA[4], bufB[4];
  LDB(bufA, 0)
#pragma unroll 1
  for (int jj = 0; jj < 6; ++jj) {
    const int j0 = 2 * jj, j1 = 2 * jj + 1;
    LDB(bufB, j1)
    CPB(bufA, j0)
    if (jj < 5) LDB(bufA, j0 + 2)
    CPB(bufB, j1)
  }

  // reduce over the 8-seg group (3 stages), write logits + cb to LDS
#pragma unroll
  for (int g = 0; g < 4; ++g) {
#pragma unroll
    for (int hh = 0; hh < 6; ++hh) {
      float s = acc[g][hh];
      s += __shfl_xor(s, 4);
      s += __shfl_xor(s, 2);
      s += __shfl_xor(s, 1);
      if (seg == 0)
        attn_s[h0 + hh][rq * 32 + g * 8 + rowi] = s + cb_s[h0 + hh];
    }
  }
  __syncthreads();

  // coalesced store: log_ws[bl][h][nq*64 .. +64), per-bl stride 768 f4
  for (int i = t; i < NHEAD * 64 / 4; i += 256) {
    const int h = i >> 4, r4 = i & 15;
    ((float4*)log_ws)[(size_t)bl * (NHEAD * NN / 4) + h * (NN / 4) + nq * 16 + r4] =
        ((const float4*)attn_s)[i];
  }
}

// =====================================================================
// C: softmax over n per (bl, h) + write out[b][n][l][h]. 768 blocks
// (round-9 proven, unchanged).
// =====================================================================
__global__ __launch_bounds__(256)
void seqw_c(const float* __restrict__ log_ws, float* __restrict__ out)
{
  __shared__ float at[NHEAD][NN];
  __shared__ float smax[NHEAD], sinv[NHEAD];
  const int t    = threadIdx.x;
  const int lane = t & 63;
  const int wv   = t >> 6;
  const int bl   = blockIdx.x;
  const int b    = bl / LL;
  const int l    = bl - b * LL;

  for (int i = t; i < NHEAD * NN / 4; i += 256)
    ((float4*)at)[i] = ((const float4*)log_ws)[(size_t)bl * (NHEAD * NN / 4) + i];
  __syncthreads();

#pragma unroll
  for (int jh = 0; jh < 3; ++jh) {
    const int h = wv * 3 + jh;
    float v0 = at[h][lane];
    float v1 = at[h][lane + 64];
    float v2 = at[h][lane + 128];
    float v3 = at[h][lane + 192];
    float mx = fmaxf(fmaxf(v0, v1), fmaxf(v2, v3));
#pragma unroll
    for (int m = 32; m; m >>= 1) mx = fmaxf(mx, __shfl_xor(mx, m));
    float s = __expf(v0 - mx) + __expf(v1 - mx) + __expf(v2 - mx) + __expf(v3 - mx);
#pragma unroll
    for (int m = 32; m; m >>= 1) s += __shfl_xor(s, m);
    if (lane == 0) { smax[h] = mx; sinv[h] = 1.0f / s; }
  }
  __syncthreads();

  {
    float o[NHEAD];
#pragma unroll
    for (int h = 0; h < NHEAD; ++h)
      o[h] = __expf(at[h][t] - smax[h]) * sinv[h];
    float* ob = out + ((size_t)(b * NN + t) * LL + l) * NHEAD;
    ((float4*)ob)[0] = make_float4(o[0], o[1], o[2],  o[3]);
    ((float4*)ob)[1] = make_float4(o[4], o[5], o[6],  o[7]);
    ((float4*)ob)[2] = make_float4(o[8], o[9], o[10], o[11]);
  }
}

// =====================================================================
// Fallback: fused single kernel (only if ws too small) — round-3 proven.
// =====================================================================
struct SmemF {
  float tar[D_MSA];
  float q[D_MSA];
  float wf[NHEAD][D_MSA];
  float cb[NHEAD];
  float smax[NHEAD];
  float sinv[NHEAD];
  float attn[NHEAD][NN];
};

__global__ __launch_bounds__(512, 2)
void seqw_fused_fb(const float* __restrict__ msa, const float* __restrict__ Wq,
                   const float* __restrict__ bq, const float* __restrict__ Wk,
                   const float* __restrict__ bk, float* __restrict__ out)
{
  __shared__ SmemF sm;
  const int t    = threadIdx.x;
  const int lane = t & 63;
  const int wv   = t >> 6;
  const int rowi = lane >> 4;
  const int seg  = lane & 15;
  const int bl   = blockIdx.x;
  const int b    = bl / LL;
  const int l    = bl - b * LL;
  const float scale = 0.17677669529663687f;

  const float* targ = msa + ((size_t)(b * NN) * LL + l) * D_MSA;
  if (t < 96) ((float4*)sm.tar)[t] = ((const float4*)targ)[t];
  __syncthreads();

  {
    float2 t2[3];
#pragma unroll
    for (int p = 0; p < 3; ++p) t2[p] = *(const float2*)&sm.tar[2 * lane + 128 * p];
#pragma unroll 1
    for (int j = 0; j < 48; ++j) {
      const int r = wv * 48 + j;
      const float* wr = Wq + (size_t)r * D_MSA;
      float s = 0.f;
#pragma unroll
      for (int p = 0; p < 3; ++p) {
        float2 w2 = *(const float2*)&wr[2 * lane + 128 * p];
        s = fmaf(t2[p].x, w2.x, s);
        s = fmaf(t2[p].y, w2.y, s);
      }
#pragma unroll
      for (int m = 32; m; m >>= 1) s += __shfl_xor(s, m);
      if (lane == 0) sm.q[r] = scale * (s + bq[r]);
    }
  }
  __syncthreads();

  if (t < D_MSA) {
    const int c = t;
    float a[NHEAD];
#pragma unroll
    for (int h = 0; h < NHEAD; ++h) a[h] = 0.f;
#pragma unroll 1
    for (int d = 0; d < DHID; ++d) {
#pragma unroll
      for (int h = 0; h < NHEAD; ++h)
        a[h] = fmaf(sm.q[h * DHID + d], Wk[(size_t)(h * DHID + d) * D_MSA + c], a[h]);
    }
#pragma unroll
    for (int h = 0; h < NHEAD; ++h) sm.wf[h][c] = a[h];
  }
  if (t < NHEAD) {
    float s = 0.f;
#pragma unroll
    for (int d = 0; d < DHID; ++d) s = fmaf(sm.q[t * DHID + d], bk[t * DHID + d], s);
    sm.cb[t] = s;
  }
  __syncthreads();

  const size_t rstride = (size_t)LL * D_MSA;
  const float* lanebase =
      msa + ((size_t)(b * NN + wv * 32 + rowi) * LL + l) * D_MSA + seg * 4;

#define LDF(buf, base, j)                                                       \
  {                                                                             \
    buf[0] = *(const float4*)((base) + 64 * (j));                               \
    buf[1] = *(const float4*)((base) + 4 * rstride + 64 * (j));                 \
  }
#define CPF(buf, j)                                                             \
  {                                                                             \
    _Pragma("unroll")                                                           \
    for (int h = 0; h < NHEAD; ++h) {                                           \
      float4 w4 = *(const float4*)&sm.wf[h][64 * (j) + 4 * seg];                \
      acc[0][h] = fmaf(buf[0].x, w4.x, acc[0][h]);                              \
      acc[0][h] = fmaf(buf[0].y, w4.y, acc[0][h]);                              \
      acc[0][h] = fmaf(buf[0].z, w4.z, acc[0][h]);                              \
      acc[0][h] = fmaf(buf[0].w, w4.w, acc[0][h]);                              \
      acc[1][h] = fmaf(buf[1].x, w4.x, acc[1][h]);                              \
      acc[1][h] = fmaf(buf[1].y, w4.y, acc[1][h]);                              \
      acc[1][h] = fmaf(buf[1].z, w4.z, acc[1][h]);                              \
      acc[1][h] = fmaf(buf[1].w, w4.w, acc[1][h]);                              \
    }                                                                           \
  }

  const float* pcur = lanebase;
  float4 bufA[2], bufB[2];
  LDF(bufA, pcur, 0)
#pragma unroll 1
  for (int ch = 0; ch < 4; ++ch) {
    float acc[2][NHEAD];
#pragma unroll
    for (int g = 0; g < 2; ++g)
#pragma unroll
      for (int h = 0; h < NHEAD; ++h) acc[g][h] = 0.f;
    const float* pnext = pcur + 8 * rstride;
    LDF(bufB, pcur, 1)  CPF(bufA, 0)
    LDF(bufA, pcur, 2)  CPF(bufB, 1)
    LDF(bufB, pcur, 3)  CPF(bufA, 2)
    LDF(bufA, pcur, 4)  CPF(bufB, 3)
    LDF(bufB, pcur, 5)  CPF(bufA, 4)
    if (ch < 3) LDF(bufA, pnext, 0)
    CPF(bufB, 5)
#pragma unroll
    for (int g = 0; g < 2; ++g) {
      const int n = wv * 32 + ch * 8 + g * 4 + rowi;
#pragma unroll
      for (int h = 0; h < NHEAD; ++h) {
        float s = acc[g][h];
        s += __shfl_xor(s, 8);
        s += __shfl_xor(s, 4);
        s += __shfl_xor(s, 2);
        s += __shfl_xor(s, 1);
        if (seg == 0) sm.attn[h][n] = s + sm.cb[h];
      }
    }
    pcur = pnext;
  }
  __syncthreads();

  if (wv < 6) {
#pragma unroll
    for (int jh = 0; jh < 2; ++jh) {
      const int h = wv * 2 + jh;
      float v0 = sm.attn[h][lane];
      float v1 = sm.attn[h][lane + 64];
      float v2 = sm.attn[h][lane + 128];
      float v3 = sm.attn[h][lane + 192];
      float mx = fmaxf(fmaxf(v0, v1), fmaxf(v2, v3));
#pragma unroll
      for (int m = 32; m; m >>= 1) mx = fmaxf(mx, __shfl_xor(mx, m));
      float s = __expf(v0 - mx) + __expf(v1 - mx) + __expf(v2 - mx) + __expf(v3 - mx);
#pragma unroll
      for (int m = 32; m; m >>= 1) s += __shfl_xor(s, m);
      if (lane == 0) { sm.smax[h] = mx; sm.sinv[h] = 1.0f / s; }
    }
  }
  __syncthreads();

  if (t < NN) {
    float o[NHEAD];
#pragma unroll
    for (int h = 0; h < NHEAD; ++h)
      o[h] = __expf(sm.attn[h][t] - sm.smax[h]) * sm.sinv[h];
    float* ob = out + ((size_t)(b * NN + t) * LL + l) * NHEAD;
    ((float4*)ob)[0] = make_float4(o[0], o[1], o[2],  o[3]);
    ((float4*)ob)[1] = make_float4(o[4], o[5], o[6],  o[7]);
    ((float4*)ob)[2] = make_float4(o[8], o[9], o[10], o[11]);
  }
}

extern "C" void kernel_launch(void* const* d_in, const int* in_sizes, int n_in,
                              void* d_out, int out_size, void* d_ws, size_t ws_size,
                              hipStream_t stream) {
  const float* msa = (const float*)d_in[0];
  const float* Wq  = (const float*)d_in[1];
  const float* bq  = (const float*)d_in[2];
  const float* Wk  = (const float*)d_in[3];
  const float* bk  = (const float*)d_in[4];
  float* out = (float*)d_out;

  if (ws_size >= WS_BYTES) {
    float* ws     = (float*)d_ws;
    float* wf_ws  = ws + WF_OFF;
    float* q_ws   = ws + Q_OFF;
    float* cb_ws  = ws + CB_OFF;
    float* log_ws = ws + LOG_OFF;
    seqw_a1<<<dim3(NBL / 3), dim3(256), 0, stream>>>(msa, Wq, bq, bk, q_ws, cb_ws);
    seqw_a2<<<dim3(NHEAD * (NBL / 16)), dim3(256), 0, stream>>>(Wk, q_ws, wf_ws);
    seqw_b<<<dim3(NBL * 4), dim3(256), 0, stream>>>(msa, wf_ws, cb_ws, log_ws);
    seqw_c<<<dim3(NBL), dim3(256), 0, stream>>>(log_ws, out);
  } else {
    seqw_fused_fb<<<dim3(NBL), dim3(512), 0, stream>>>(msa, Wq, bq, Wk, bk, out);
  }
}

// Round 15
// 128.316 us; speedup vs baseline: 1.1789x; 1.0173x over previous
//
#include <hip/hip_runtime.h>
#include <hip/hip_bf16.h>

#define D_MSA 384
#define NHEAD 12
#define DHID  32
#define BB    2
#define NN    256
#define LL    384
#define NBL   (BB * LL)          // 768 (b,l) pairs
#define WFROW (NHEAD * D_MSA)    // 4608

// ---- workspace layout (in floats) ----
#define WF_OFF 0
#define WF_SZ  ((size_t)NBL * WFROW)       // 3,538,944
#define Q_OFF  (WF_OFF + WF_SZ)
#define Q_SZ   ((size_t)NBL * D_MSA)       // 294,912
#define CB_OFF (Q_OFF + Q_SZ)
#define CB_SZ  ((size_t)NBL * NHEAD)       // 9,216
#define LOG_OFF (CB_OFF + CB_SZ)
#define LOG_SZ ((size_t)NBL * NHEAD * NN)  // 2,359,296
#define WS_FLOATS (LOG_OFF + LOG_SZ)
#define WS_BYTES  (WS_FLOATS * 4)

// =====================================================================
// A1: q[bl][c] = scale*(tar[bl] . Wq[c,:] + bq[c]); cb[bl][h] = q_h . bk_h
// 256 blocks x 3 bl-rows, 256 thr (round-9 proven, unchanged).
// =====================================================================
__global__ __launch_bounds__(256)
void seqw_a1(const float* __restrict__ msa, const float* __restrict__ Wq,
             const float* __restrict__ bq, const float* __restrict__ bk,
             float* __restrict__ q_ws, float* __restrict__ cb_ws)
{
  __shared__ float tar[3][D_MSA];
  __shared__ float qs[3][D_MSA];
  const int t    = threadIdx.x;
  const int lane = t & 63;
  const int wv   = t >> 6;        // 0..3
  const int rowi = lane >> 4;     // 0..3
  const int seg  = lane & 15;     // 0..15
  const int bl0  = blockIdx.x * 3;
  const int b    = bl0 / LL, l0 = bl0 % LL;  // 3 | 384, never straddles b
  const float scale = 0.17677669529663687f;  // 1/sqrt(32)

  const float* base = msa + ((size_t)b * NN * LL + l0) * D_MSA;
  for (int i = t; i < 3 * D_MSA / 4; i += 256)
    ((float4*)tar)[i] = ((const float4*)base)[i];
  __syncthreads();

#pragma unroll 1
  for (int cc = 0; cc < 24; ++cc) {
    const int c = wv * 96 + cc * 4 + rowi;
    const float* wr = Wq + (size_t)c * D_MSA + seg * 4;
    float a0 = 0.f, a1 = 0.f, a2 = 0.f;
#pragma unroll
    for (int j = 0; j < 6; ++j) {
      float4 w4 = *(const float4*)(wr + 64 * j);
      float4 t0 = *(const float4*)&tar[0][64 * j + seg * 4];
      float4 t1 = *(const float4*)&tar[1][64 * j + seg * 4];
      float4 t2 = *(const float4*)&tar[2][64 * j + seg * 4];
      a0 = fmaf(w4.x, t0.x, a0); a0 = fmaf(w4.y, t0.y, a0);
      a0 = fmaf(w4.z, t0.z, a0); a0 = fmaf(w4.w, t0.w, a0);
      a1 = fmaf(w4.x, t1.x, a1); a1 = fmaf(w4.y, t1.y, a1);
      a1 = fmaf(w4.z, t1.z, a1); a1 = fmaf(w4.w, t1.w, a1);
      a2 = fmaf(w4.x, t2.x, a2); a2 = fmaf(w4.y, t2.y, a2);
      a2 = fmaf(w4.z, t2.z, a2); a2 = fmaf(w4.w, t2.w, a2);
    }
#pragma unroll
    for (int m = 8; m; m >>= 1) {
      a0 += __shfl_xor(a0, m);
      a1 += __shfl_xor(a1, m);
      a2 += __shfl_xor(a2, m);
    }
    if (seg == 0) {
      const float bqc = bq[c];
      const float q0 = scale * (a0 + bqc);
      const float q1 = scale * (a1 + bqc);
      const float q2 = scale * (a2 + bqc);
      qs[0][c] = q0; q_ws[(size_t)(bl0 + 0) * D_MSA + c] = q0;
      qs[1][c] = q1; q_ws[(size_t)(bl0 + 1) * D_MSA + c] = q1;
      qs[2][c] = q2; q_ws[(size_t)(bl0 + 2) * D_MSA + c] = q2;
    }
  }
  __syncthreads();

  if (t < 3 * NHEAD) {
    const int r = t / NHEAD, h = t % NHEAD;
    float s = 0.f;
#pragma unroll
    for (int d = 0; d < DHID; ++d)
      s = fmaf(qs[r][h * DHID + d], bk[h * DHID + d], s);
    cb_ws[(size_t)(bl0 + r) * NHEAD + h] = s;
  }
}

// =====================================================================
// A2: wf[bl][h][c] = sum_d q[bl][h*32+d] * Wk[h*32+d][c]
// grid 12h x 48 tiles of 16 bl-rows, 256 threads (round-9 proven).
// =====================================================================
__global__ __launch_bounds__(256)
void seqw_a2(const float* __restrict__ Wk, const float* __restrict__ q_ws,
             float* __restrict__ wf_ws)
{
  __shared__ float qt[16][DHID];
  const int t   = threadIdx.x;
  const int h   = blockIdx.x % NHEAD;
  const int bl0 = (blockIdx.x / NHEAD) * 16;

  if (t < 128) {
    const int r = t >> 3, j = (t & 7) * 4;
    *(float4*)&qt[r][j] =
        *(const float4*)(q_ws + (size_t)(bl0 + r) * D_MSA + h * DHID + j);
  }
  __syncthreads();

#pragma unroll 1
  for (int pass = 0; pass < 2; ++pass) {
    const int c = pass * 256 + t;
    if (c < D_MSA) {
      float acc[16];
#pragma unroll
      for (int r = 0; r < 16; ++r) acc[r] = 0.f;
      const float* wkb = Wk + (size_t)(h * DHID) * D_MSA + c;
#pragma unroll 2
      for (int d = 0; d < DHID; d += 4) {
        const float w0 = wkb[(size_t)(d + 0) * D_MSA];
        const float w1 = wkb[(size_t)(d + 1) * D_MSA];
        const float w2 = wkb[(size_t)(d + 2) * D_MSA];
        const float w3 = wkb[(size_t)(d + 3) * D_MSA];
#pragma unroll
        for (int r = 0; r < 16; ++r) {
          float4 q4 = *(const float4*)&qt[r][d];
          acc[r] = fmaf(q4.x, w0, acc[r]);
          acc[r] = fmaf(q4.y, w1, acc[r]);
          acc[r] = fmaf(q4.z, w2, acc[r]);
          acc[r] = fmaf(q4.w, w3, acc[r]);
        }
      }
#pragma unroll
      for (int r = 0; r < 16; ++r)
        wf_ws[(size_t)(bl0 + r) * WFROW + h * D_MSA + c] = acc[r];
    }
  }
}

// =====================================================================
// B: logits only. Grid 3072 = (bl, n-quarter); 256 thr = 4 waves.
// ROUND-15 CHANGE (only change vs round 12): __launch_bounds__(256, 3)
// — cap VGPR at ~168 to prevent the greedy-allocator occupancy collapse
// measured in round 7 (184 VGPR -> 8 waves/CU -> 720 GB/s). Live state
// is ~80 regs (acc 24 + bufs 32 + addr), margin ~88 >> the spill cases
// (r5 margin 15, r6 margin 60), so no-spill expected.
// Wave wv: head-group hg = wv&1 (6 heads), row-half rq = wv>>1.
// Lanes = 8 rowi x 8 seg; 128B/row coalesced loads; wf staged in LDS
// (round-13: global-direct wf costs +21us). acc[4][6]=24 regs.
// =====================================================================
__global__ __launch_bounds__(256, 3)
void seqw_b(const float* __restrict__ msa, const float* __restrict__ wf_ws,
            const float* __restrict__ cb_ws, float* __restrict__ log_ws)
{
  __shared__ float wf_s[NHEAD][D_MSA];   // 18 KB
  __shared__ float cb_s[NHEAD];
  __shared__ float attn_s[NHEAD][64];    // 3 KB
  const int t    = threadIdx.x;
  const int lane = t & 63;
  const int wv   = t >> 6;        // 0..3
  const int hg   = wv & 1;        // head group: h0 = 6*hg
  const int rq   = wv >> 1;       // row half: rows [rq*32, rq*32+32)
  const int h0   = 6 * hg;
  const int rowi = lane >> 3;     // 0..7
  const int seg  = lane & 7;      // 0..7 : 8 lanes cover 32 c per j-step
  const int bid  = blockIdx.x;
  const int bl   = bid >> 2;
  const int nq   = bid & 3;       // which 64-row quarter
  const int b    = bl / LL;
  const int l    = bl - b * LL;

  // stage wf slice (1152 float4, coalesced; 4 quarters share via L2) + cb
  {
    const float4* src = (const float4*)(wf_ws + (size_t)bl * WFROW);
    for (int i = t; i < WFROW / 4; i += 256) ((float4*)wf_s)[i] = src[i];
    if (t < NHEAD) cb_s[t] = cb_ws[(size_t)bl * NHEAD + t];
  }
  __syncthreads();

  const size_t rstride = (size_t)LL * D_MSA;
  const float* lanebase =
      msa + ((size_t)(b * NN + nq * 64 + rq * 32 + rowi) * LL + l) * D_MSA + seg * 4;

  // LDB: 4 row-groups; 8-lane seg group reads 128B contiguous per row
#define LDB(buf, j)                                                             \
  {                                                                             \
    _Pragma("unroll")                                                           \
    for (int g = 0; g < 4; ++g)                                                 \
      buf[g] = *(const float4*)(lanebase + (size_t)(g * 8) * rstride + 32 * (j)); \
  }
  // CPB: 6 w4 reads serve 4 rows x 6 heads
#define CPB(buf, j)                                                             \
  {                                                                             \
    _Pragma("unroll")                                                           \
    for (int hh = 0; hh < 6; ++hh) {                                            \
      float4 w4 = *(const float4*)&wf_s[h0 + hh][32 * (j) + 4 * seg];           \
      _Pragma("unroll")                                                         \
      for (int g = 0; g < 4; ++g) {                                             \
        acc[g][hh] = fmaf(buf[g].x, w4.x, acc[g][hh]);                          \
        acc[g][hh] = fmaf(buf[g].y, w4.y, acc[g][hh]);                          \
        acc[g][hh] = fmaf(buf[g].z, w4.z, acc[g][hh]);                          \
        acc[g][hh] = fmaf(buf[g].w, w4.w, acc[g][hh]);                          \
      }                                                                         \
    }                                                                           \
  }

  float acc[4][6];
#pragma unroll
  for (int g = 0; g < 4; ++g)
#pragma unroll
    for (int hh = 0; hh < 6; ++hh) acc[g][hh] = 0.f;

  float4 bufA[4], bufB[4];
  LDB(bufA, 0)
#pragma unroll 1
  for (int jj = 0; jj < 6; ++jj) {
    const int j0 = 2 * jj, j1 = 2 * jj + 1;
    LDB(bufB, j1)
    CPB(bufA, j0)
    if (jj < 5) LDB(bufA, j0 + 2)
    CPB(bufB, j1)
  }

  // reduce over the 8-seg group (3 stages), write logits + cb to LDS
#pragma unroll
  for (int g = 0; g < 4; ++g) {
#pragma unroll
    for (int hh = 0; hh < 6; ++hh) {
      float s = acc[g][hh];
      s += __shfl_xor(s, 4);
      s += __shfl_xor(s, 2);
      s += __shfl_xor(s, 1);
      if (seg == 0)
        attn_s[h0 + hh][rq * 32 + g * 8 + rowi] = s + cb_s[h0 + hh];
    }
  }
  __syncthreads();

  // coalesced store: log_ws[bl][h][nq*64 .. +64), per-bl stride 768 f4
  for (int i = t; i < NHEAD * 64 / 4; i += 256) {
    const int h = i >> 4, r4 = i & 15;
    ((float4*)log_ws)[(size_t)bl * (NHEAD * NN / 4) + h * (NN / 4) + nq * 16 + r4] =
        ((const float4*)attn_s)[i];
  }
}

// =====================================================================
// C: softmax over n per (bl, h) + write out[b][n][l][h]. 768 blocks
// (round-9 proven, unchanged).
// =====================================================================
__global__ __launch_bounds__(256)
void seqw_c(const float* __restrict__ log_ws, float* __restrict__ out)
{
  __shared__ float at[NHEAD][NN];
  __shared__ float smax[NHEAD], sinv[NHEAD];
  const int t    = threadIdx.x;
  const int lane = t & 63;
  const int wv   = t >> 6;
  const int bl   = blockIdx.x;
  const int b    = bl / LL;
  const int l    = bl - b * LL;

  for (int i = t; i < NHEAD * NN / 4; i += 256)
    ((float4*)at)[i] = ((const float4*)log_ws)[(size_t)bl * (NHEAD * NN / 4) + i];
  __syncthreads();

#pragma unroll
  for (int jh = 0; jh < 3; ++jh) {
    const int h = wv * 3 + jh;
    float v0 = at[h][lane];
    float v1 = at[h][lane + 64];
    float v2 = at[h][lane + 128];
    float v3 = at[h][lane + 192];
    float mx = fmaxf(fmaxf(v0, v1), fmaxf(v2, v3));
#pragma unroll
    for (int m = 32; m; m >>= 1) mx = fmaxf(mx, __shfl_xor(mx, m));
    float s = __expf(v0 - mx) + __expf(v1 - mx) + __expf(v2 - mx) + __expf(v3 - mx);
#pragma unroll
    for (int m = 32; m; m >>= 1) s += __shfl_xor(s, m);
    if (lane == 0) { smax[h] = mx; sinv[h] = 1.0f / s; }
  }
  __syncthreads();

  {
    float o[NHEAD];
#pragma unroll
    for (int h = 0; h < NHEAD; ++h)
      o[h] = __expf(at[h][t] - smax[h]) * sinv[h];
    float* ob = out + ((size_t)(b * NN + t) * LL + l) * NHEAD;
    ((float4*)ob)[0] = make_float4(o[0], o[1], o[2],  o[3]);
    ((float4*)ob)[1] = make_float4(o[4], o[5], o[6],  o[7]);
    ((float4*)ob)[2] = make_float4(o[8], o[9], o[10], o[11]);
  }
}

// =====================================================================
// Fallback: fused single kernel (only if ws too small) — round-3 proven.
// =====================================================================
struct SmemF {
  float tar[D_MSA];
  float q[D_MSA];
  float wf[NHEAD][D_MSA];
  float cb[NHEAD];
  float smax[NHEAD];
  float sinv[NHEAD];
  float attn[NHEAD][NN];
};

__global__ __launch_bounds__(512, 2)
void seqw_fused_fb(const float* __restrict__ msa, const float* __restrict__ Wq,
                   const float* __restrict__ bq, const float* __restrict__ Wk,
                   const float* __restrict__ bk, float* __restrict__ out)
{
  __shared__ SmemF sm;
  const int t    = threadIdx.x;
  const int lane = t & 63;
  const int wv   = t >> 6;
  const int rowi = lane >> 4;
  const int seg  = lane & 15;
  const int bl   = blockIdx.x;
  const int b    = bl / LL;
  const int l    = bl - b * LL;
  const float scale = 0.17677669529663687f;

  const float* targ = msa + ((size_t)(b * NN) * LL + l) * D_MSA;
  if (t < 96) ((float4*)sm.tar)[t] = ((const float4*)targ)[t];
  __syncthreads();

  {
    float2 t2[3];
#pragma unroll
    for (int p = 0; p < 3; ++p) t2[p] = *(const float2*)&sm.tar[2 * lane + 128 * p];
#pragma unroll 1
    for (int j = 0; j < 48; ++j) {
      const int r = wv * 48 + j;
      const float* wr = Wq + (size_t)r * D_MSA;
      float s = 0.f;
#pragma unroll
      for (int p = 0; p < 3; ++p) {
        float2 w2 = *(const float2*)&wr[2 * lane + 128 * p];
        s = fmaf(t2[p].x, w2.x, s);
        s = fmaf(t2[p].y, w2.y, s);
      }
#pragma unroll
      for (int m = 32; m; m >>= 1) s += __shfl_xor(s, m);
      if (lane == 0) sm.q[r] = scale * (s + bq[r]);
    }
  }
  __syncthreads();

  if (t < D_MSA) {
    const int c = t;
    float a[NHEAD];
#pragma unroll
    for (int h = 0; h < NHEAD; ++h) a[h] = 0.f;
#pragma unroll 1
    for (int d = 0; d < DHID; ++d) {
#pragma unroll
      for (int h = 0; h < NHEAD; ++h)
        a[h] = fmaf(sm.q[h * DHID + d], Wk[(size_t)(h * DHID + d) * D_MSA + c], a[h]);
    }
#pragma unroll
    for (int h = 0; h < NHEAD; ++h) sm.wf[h][c] = a[h];
  }
  if (t < NHEAD) {
    float s = 0.f;
#pragma unroll
    for (int d = 0; d < DHID; ++d) s = fmaf(sm.q[t * DHID + d], bk[t * DHID + d], s);
    sm.cb[t] = s;
  }
  __syncthreads();

  const size_t rstride = (size_t)LL * D_MSA;
  const float* lanebase =
      msa + ((size_t)(b * NN + wv * 32 + rowi) * LL + l) * D_MSA + seg * 4;

#define LDF(buf, base, j)                                                       \
  {                                                                             \
    buf[0] = *(const float4*)((base) + 64 * (j));                               \
    buf[1] = *(const float4*)((base) + 4 * rstride + 64 * (j));                 \
  }
#define CPF(buf, j)                                                             \
  {                                                                             \
    _Pragma("unroll")                                                           \
    for (int h = 0; h < NHEAD; ++h) {                                           \
      float4 w4 = *(const float4*)&sm.wf[h][64 * (j) + 4 * seg];                \
      acc[0][h] = fmaf(buf[0].x, w4.x, acc[0][h]);                              \
      acc[0][h] = fmaf(buf[0].y, w4.y, acc[0][h]);                              \
      acc[0][h] = fmaf(buf[0].z, w4.z, acc[0][h]);                              \
      acc[0][h] = fmaf(buf[0].w, w4.w, acc[0][h]);                              \
      acc[1][h] = fmaf(buf[1].x, w4.x, acc[1][h]);                              \
      acc[1][h] = fmaf(buf[1].y, w4.y, acc[1][h]);                              \
      acc[1][h] = fmaf(buf[1].z, w4.z, acc[1][h]);                              \
      acc[1][h] = fmaf(buf[1].w, w4.w, acc[1][h]);                              \
    }                                                                           \
  }

  const float* pcur = lanebase;
  float4 bufA[2], bufB[2];
  LDF(bufA, pcur, 0)
#pragma unroll 1
  for (int ch = 0; ch < 4; ++ch) {
    float acc[2][NHEAD];
#pragma unroll
    for (int g = 0; g < 2; ++g)
#pragma unroll
      for (int h = 0; h < NHEAD; ++h) acc[g][h] = 0.f;
    const float* pnext = pcur + 8 * rstride;
    LDF(bufB, pcur, 1)  CPF(bufA, 0)
    LDF(bufA, pcur, 2)  CPF(bufB, 1)
    LDF(bufB, pcur, 3)  CPF(bufA, 2)
    LDF(bufA, pcur, 4)  CPF(bufB, 3)
    LDF(bufB, pcur, 5)  CPF(bufA, 4)
    if (ch < 3) LDF(bufA, pnext, 0)
    CPF(bufB, 5)
#pragma unroll
    for (int g = 0; g < 2; ++g) {
      const int n = wv * 32 + ch * 8 + g * 4 + rowi;
#pragma unroll
      for (int h = 0; h < NHEAD; ++h) {
        float s = acc[g][h];
        s += __shfl_xor(s, 8);
        s += __shfl_xor(s, 4);
        s += __shfl_xor(s, 2);
        s += __shfl_xor(s, 1);
        if (seg == 0) sm.attn[h][n] = s + sm.cb[h];
      }
    }
    pcur = pnext;
  }
  __syncthreads();

  if (wv < 6) {
#pragma unroll
    for (int jh = 0; jh < 2; ++jh) {
      const int h = wv * 2 + jh;
      float v0 = sm.attn[h][lane];
      float v1 = sm.attn[h][lane + 64];
      float v2 = sm.attn[h][lane + 128];
      float v3 = sm.attn[h][lane + 192];
      float mx = fmaxf(fmaxf(v0, v1), fmaxf(v2, v3));
#pragma unroll
      for (int m = 32; m; m >>= 1) mx = fmaxf(mx, __shfl_xor(mx, m));
      float s = __expf(v0 - mx) + __expf(v1 - mx) + __expf(v2 - mx) + __expf(v3 - mx);
#pragma unroll
      for (int m = 32; m; m >>= 1) s += __shfl_xor(s, m);
      if (lane == 0) { sm.smax[h] = mx; sm.sinv[h] = 1.0f / s; }
    }
  }
  __syncthreads();

  if (t < NN) {
    float o[NHEAD];
#pragma unroll
    for (int h = 0; h < NHEAD; ++h)
      o[h] = __expf(sm.attn[h][t] - sm.smax[h]) * sm.sinv[h];
    float* ob = out + ((size_t)(b * NN + t) * LL + l) * NHEAD;
    ((float4*)ob)[0] = make_float4(o[0], o[1], o[2],  o[3]);
    ((float4*)ob)[1] = make_float4(o[4], o[5], o[6],  o[7]);
    ((float4*)ob)[2] = make_float4(o[8], o[9], o[10], o[11]);
  }
}

extern "C" void kernel_launch(void* const* d_in, const int* in_sizes, int n_in,
                              void* d_out, int out_size, void* d_ws, size_t ws_size,
                              hipStream_t stream) {
  const float* msa = (const float*)d_in[0];
  const float* Wq  = (const float*)d_in[1];
  const float* bq  = (const float*)d_in[2];
  const float* Wk  = (const float*)d_in[3];
  const float* bk  = (const float*)d_in[4];
  float* out = (float*)d_out;

  if (ws_size >= WS_BYTES) {
    float* ws     = (float*)d_ws;
    float* wf_ws  = ws + WF_OFF;
    float* q_ws   = ws + Q_OFF;
    float* cb_ws  = ws + CB_OFF;
    float* log_ws = ws + LOG_OFF;
    seqw_a1<<<dim3(NBL / 3), dim3(256), 0, stream>>>(msa, Wq, bq, bk, q_ws, cb_ws);
    seqw_a2<<<dim3(NHEAD * (NBL / 16)), dim3(256), 0, stream>>>(Wk, q_ws, wf_ws);
    seqw_b<<<dim3(NBL * 4), dim3(256), 0, stream>>>(msa, wf_ws, cb_ws, log_ws);
    seqw_c<<<dim3(NBL), dim3(256), 0, stream>>>(log_ws, out);
  } else {
    seqw_fused_fb<<<dim3(NBL), dim3(512), 0, stream>>>(msa, Wq, bq, Wk, bk, out);
  }
}